// Round 6
// baseline (91.614 us; speedup 1.0000x reference)
//
#include <hip/hip_runtime.h>
#include <hip/hip_bf16.h>

// CFAR via separable box sums — R12: R11 structure, segscan made in-place
// (Btot doubles as SP) so workspace stays at 40 MB (R10-proven footprint).
//   hbv     : per 4-row segment (NSEG=256 -> 1024 blocks, 4/CU, 16 waves/CU):
//             4 waves write padded prefix rows P[0..3]; ONE barrier; then all
//             threads read window diffs straight from P (scalar conflict-free
//             LDS reads, no Hx transpose buffer) and accumulate the running
//             column prefix in registers. Writes scanned g161/g321 + totals.
//   segscan : exclusive scan of 256 segment totals per column, IN PLACE on
//             Btot; wave owns 64 segs in registers via coalesced loads
//             (all reads precede all writes per thread), LDS cross-wave fixup.
//   final   : front = P(r+80)-P(r-81), allsum = P(r+160)-P(r-161),
//             P(rho) = g[rho] + SP[rho>>2] ; out = SCALE*front/(allsum-front)
// BG_AREA = 321^2-161^2 = 77120 ; FRONT_DIV = 161^2*1.8 = 46657.8

#define IMG 4
#define H 1024
#define W 1024
#define SEGR 4
#define NSEG 256                   // H / SEGR
#define PADL 164
#define PADR 164
#define ROWLEN (PADL + W + PADR)   // 1352 floats per padded LDS row

// ------- Kernel 1: horizontal box sums + in-register vertical segment scan --
// One block per (img, seg): 4 waves x 1 row each; 1 barrier; direct P reads.
__global__ __launch_bounds__(256) void hbv_kernel(const float* __restrict__ x,
                                                  float* __restrict__ g161,
                                                  float* __restrict__ g321,
                                                  float* __restrict__ Btot) {
    __shared__ float P[4][ROWLEN];   // 21632 B — per-wave padded prefix row
    const int wave = threadIdx.x >> 6;
    const int lane = threadIdx.x & 63;
    const int tid  = threadIdx.x;
    const int blk  = blockIdx.x;             // img*NSEG + seg
    const size_t rowbase = (size_t)blk << 2; // first flat row of segment

    // ---- phase 1: row prefix into padded LDS row (per wave, own row)
    {
        const size_t row = rowbase + wave;
        const float4* xr = reinterpret_cast<const float4*>(x + row * W);
        float v[16];
        float4 a0 = xr[(lane << 2) + 0];
        float4 a1 = xr[(lane << 2) + 1];
        float4 a2 = xr[(lane << 2) + 2];
        float4 a3 = xr[(lane << 2) + 3];
        v[0]=a0.x; v[1]=a0.y; v[2]=a0.z; v[3]=a0.w;
        v[4]=a1.x; v[5]=a1.y; v[6]=a1.z; v[7]=a1.w;
        v[8]=a2.x; v[9]=a2.y; v[10]=a2.z; v[11]=a2.w;
        v[12]=a3.x; v[13]=a3.y; v[14]=a3.z; v[15]=a3.w;
        float s = 0.f;
#pragma unroll
        for (int j = 0; j < 16; ++j) { s += v[j]; v[j] = s; }
        float t = s;
#pragma unroll
        for (int d = 1; d < 64; d <<= 1) {
            float u = __shfl_up(t, d, 64);
            if (lane >= d) t += u;
        }
        const float off = t - s;        // exclusive prefix of lane totals
#pragma unroll
        for (int j = 0; j < 16; ++j) v[j] += off;
        const float tot = __shfl(t, 63, 64);

        float* rowP = P[wave];
        float4* Pr = reinterpret_cast<float4*>(rowP + PADL);
        Pr[(lane << 2) + 0] = make_float4(v[0], v[1], v[2], v[3]);
        Pr[(lane << 2) + 1] = make_float4(v[4], v[5], v[6], v[7]);
        Pr[(lane << 2) + 2] = make_float4(v[8], v[9], v[10], v[11]);
        Pr[(lane << 2) + 3] = make_float4(v[12], v[13], v[14], v[15]);
        // pads: quads 0..40 = 0 (left), quads 297..337 = tot (right)
        float4* Pz = reinterpret_cast<float4*>(rowP);
        if (lane < 41) {
            Pz[lane]       = make_float4(0.f, 0.f, 0.f, 0.f);
            Pz[297 + lane] = make_float4(tot, tot, tot, tot);
        }
    }
    __syncthreads();   // the only barrier

    // ---- phase 2: direct window diffs from P + running column prefix.
    // Thread owns scalar columns {tid, tid+256, tid+512, tid+768}:
    // consecutive LDS addresses per wave (conflict-free), 256 B-coalesced
    // global stores per wave.
    float acc1[4] = {0.f, 0.f, 0.f, 0.f};
    float acc3[4] = {0.f, 0.f, 0.f, 0.f};
#pragma unroll
    for (int rr = 0; rr < SEGR; ++rr) {
        const float* Pr = &P[rr][PADL];
        float* o1 = g161 + (rowbase + rr) * W;
        float* o3 = g321 + (rowbase + rr) * W;
#pragma unroll
        for (int j = 0; j < 4; ++j) {
            const int c = tid + (j << 8);
            acc1[j] += Pr[c + 80]  - Pr[c - 81];
            acc3[j] += Pr[c + 160] - Pr[c - 161];
            o1[c] = acc1[j];
            o3[c] = acc3[j];
        }
    }

    // ---- segment totals: float layout [buf*IMG+img][seg][W]
    const int img = blk >> 8;
    const int seg = blk & 255;
    float* bt1 = Btot + ((size_t)img << 18)         + ((size_t)seg << 10);
    float* bt3 = Btot + ((size_t)(IMG + img) << 18) + ((size_t)seg << 10);
#pragma unroll
    for (int j = 0; j < 4; ++j) {
        bt1[tid + (j << 8)] = acc1[j];
        bt3[tid + (j << 8)] = acc3[j];
    }
}

// ------- Kernel 2: exclusive scan of 256 segment totals per column ---------
// IN PLACE on Btot. Block = (bufimg, 64-col group), 4 waves. Wave w: segs
// 64w..64w+63 into registers via 64 COALESCED 256 B loads (all reads precede
// all writes per thread — each element owned by exactly one thread), in-lane
// exclusive scan, wave totals -> LDS, cross-wave offset, coalesced stores.
// 128 blocks x 256.
__global__ __launch_bounds__(256) void segscan_kernel(float* __restrict__ Btot) {
    __shared__ float T[4][64];
    const int wave = threadIdx.x >> 6;
    const int lane = threadIdx.x & 63;
    const int bi   = blockIdx.x >> 4;                    // buf*IMG+img, 0..7
    const int col  = ((blockIdx.x & 15) << 6) + lane;    // 0..1023
    const size_t base = ((size_t)bi << 18) + ((size_t)(wave << 6) << 10) + col;

    float v[64];
#pragma unroll
    for (int s = 0; s < 64; ++s) v[s] = Btot[base + ((size_t)s << 10)];
    float run = 0.f;
#pragma unroll
    for (int s = 0; s < 64; ++s) { const float t = v[s]; v[s] = run; run += t; }
    T[wave][lane] = run;
    __syncthreads();
    float off = 0.f;
    for (int w = 0; w < wave; ++w) off += T[w][lane];    // wave-uniform trip
#pragma unroll
    for (int s = 0; s < 64; ++s) Btot[base + ((size_t)s << 10)] = v[s] + off;
}

// ------- Kernel 3: final — window diffs of full column prefixes ------------
// 512 threads = 2 rows x 256 quad-columns per block; rcp-based division.
__global__ __launch_bounds__(512) void final_kernel(const float* __restrict__ g161,
                                                    const float* __restrict__ g321,
                                                    const float* __restrict__ SP,
                                                    float* __restrict__ out) {
    const int img = blockIdx.x >> 9;
    const int r   = ((blockIdx.x & 511) << 1) + (threadIdx.x >> 8);
    const int c4  = threadIdx.x & 255;

    const float4* P1 = reinterpret_cast<const float4*>(g161 + ((size_t)img << 20));
    const float4* P3 = reinterpret_cast<const float4*>(g321 + ((size_t)img << 20));
    // SP float4 layout: [buf][img][NSEG][256] ; NSEG*256 = 1<<16 per (buf,img)
    const float4* SP1 = reinterpret_cast<const float4*>(SP) + ((size_t)img << 16);
    const float4* SP3 = reinterpret_cast<const float4*>(SP) + ((size_t)(IMG + img) << 16);

    const int hi1 = min(r + 80, H - 1),  lo1 = r - 81;
    const int hi3 = min(r + 160, H - 1), lo3 = r - 161;

    float4 f  = P1[((size_t)hi1 << 8) + c4];
    float4 fs = SP1[(((size_t)hi1 >> 2) << 8) + c4];
    float fx = f.x + fs.x, fy = f.y + fs.y, fz = f.z + fs.z, fw = f.w + fs.w;
    if (lo1 >= 0) {
        float4 g  = P1[((size_t)lo1 << 8) + c4];
        float4 gs = SP1[(((size_t)lo1 >> 2) << 8) + c4];
        fx -= g.x + gs.x; fy -= g.y + gs.y; fz -= g.z + gs.z; fw -= g.w + gs.w;
    }
    float4 a  = P3[((size_t)hi3 << 8) + c4];
    float4 as = SP3[(((size_t)hi3 >> 2) << 8) + c4];
    float ax = a.x + as.x, ay = a.y + as.y, az = a.z + as.z, aw = a.w + as.w;
    if (lo3 >= 0) {
        float4 g  = P3[((size_t)lo3 << 8) + c4];
        float4 gs = SP3[(((size_t)lo3 >> 2) << 8) + c4];
        ax -= g.x + gs.x; ay -= g.y + gs.y; az -= g.z + gs.z; aw -= g.w + gs.w;
    }

    const float SCALE = (float)(77120.0 / 46657.8);   // BG_AREA / FRONT_DIV
    float4 o;
    o.x = SCALE * fx * __builtin_amdgcn_rcpf(ax - fx);
    o.y = SCALE * fy * __builtin_amdgcn_rcpf(ay - fy);
    o.z = SCALE * fz * __builtin_amdgcn_rcpf(az - fz);
    o.w = SCALE * fw * __builtin_amdgcn_rcpf(aw - fw);
    reinterpret_cast<float4*>(out + ((size_t)img << 20) + ((size_t)r << 10))[c4] = o;
}

extern "C" void kernel_launch(void* const* d_in, const int* in_sizes, int n_in,
                              void* d_out, int out_size, void* d_ws, size_t ws_size,
                              hipStream_t stream) {
    const float* x = (const float*)d_in[0];
    float* outp = (float*)d_out;
    float* g161 = (float*)d_ws;                          // 16 MB (scanned)
    float* g321 = g161 + (size_t)IMG * H * W;            // 16 MB (scanned)
    float* Btot = g321 + (size_t)IMG * H * W;            // 8 MB (2*4*256*1024 fp32)
                                                         // total 40 MB (R10 footprint)

    hbv_kernel<<<dim3(IMG * NSEG), dim3(256), 0, stream>>>(x, g161, g321, Btot);
    segscan_kernel<<<dim3(128), dim3(256), 0, stream>>>(Btot);
    final_kernel<<<dim3(IMG * (H / 2)), dim3(512), 0, stream>>>(g161, g321, Btot, outp);
}

// Round 7
// 85.977 us; speedup vs baseline: 1.0656x; 1.0656x over previous
//
#include <hip/hip_runtime.h>
#include <hip/hip_bf16.h>

// CFAR via summed-area table — R13: store ONE 2D prefix Q instead of two
// window-scanned buffers; all window diffs move to the final kernel.
//   sat     : per 4-row segment (1024 blocks): 4 waves compute row prefixes
//             P[0..3] in LDS (16 KB, no pads); one barrier; each thread
//             column-accumulates its quad-col over the 4 rows and writes the
//             segment-local SAT Q (float4). 16 MB written (was 32+8).
//   segscan : SP[img][s][c] = exclusive prefix over segments of Q's segment-
//             last rows (read directly from Q — no Btot buffer).
//   final   : stage Qg rows (Q + SP fold) for hi1/lo1 then hi3/lo3 through
//             32 KB LDS; window math with column clamps:
//             front  = Qg(r+80,c+80)-Qg(r+80,c-81)-Qg(r-81,c+80)+Qg(r-81,c-81)
//             allsum = same at +-160/161 ; out = SCALE*front/(allsum-front)
//             (negative rows staged as zeros; cols clamped: <0 -> 0 term,
//              >1023 -> 1023 since row prefix saturates).
// BG_AREA = 321^2-161^2 = 77120 ; FRONT_DIV = 161^2*1.8 = 46657.8

#define IMG 4
#define H 1024
#define W 1024
#define SEGR 4
#define NSEG 256                   // H / SEGR

// ------- Kernel 1: row prefix + segment-local column prefix (SAT) ----------
__global__ __launch_bounds__(256) void sat_kernel(const float* __restrict__ x,
                                                  float* __restrict__ Q) {
    __shared__ float P[4][W];        // 16384 B — per-wave row prefix
    const int wave = threadIdx.x >> 6;
    const int lane = threadIdx.x & 63;
    const int tid  = threadIdx.x;
    const size_t rowbase = (size_t)blockIdx.x << 2;   // flat rows over images

    // ---- phase 1: row prefix into LDS (per wave, own row)
    {
        const float4* xr = reinterpret_cast<const float4*>(x + (rowbase + wave) * W);
        float v[16];
        float4 a0 = xr[(lane << 2) + 0];
        float4 a1 = xr[(lane << 2) + 1];
        float4 a2 = xr[(lane << 2) + 2];
        float4 a3 = xr[(lane << 2) + 3];
        v[0]=a0.x; v[1]=a0.y; v[2]=a0.z; v[3]=a0.w;
        v[4]=a1.x; v[5]=a1.y; v[6]=a1.z; v[7]=a1.w;
        v[8]=a2.x; v[9]=a2.y; v[10]=a2.z; v[11]=a2.w;
        v[12]=a3.x; v[13]=a3.y; v[14]=a3.z; v[15]=a3.w;
        float s = 0.f;
#pragma unroll
        for (int j = 0; j < 16; ++j) { s += v[j]; v[j] = s; }
        float t = s;
#pragma unroll
        for (int d = 1; d < 64; d <<= 1) {
            float u = __shfl_up(t, d, 64);
            if (lane >= d) t += u;
        }
        const float off = t - s;        // exclusive prefix of lane totals
#pragma unroll
        for (int j = 0; j < 16; ++j) v[j] += off;

        float4* Pr = reinterpret_cast<float4*>(P[wave]);
        Pr[(lane << 2) + 0] = make_float4(v[0], v[1], v[2], v[3]);
        Pr[(lane << 2) + 1] = make_float4(v[4], v[5], v[6], v[7]);
        Pr[(lane << 2) + 2] = make_float4(v[8], v[9], v[10], v[11]);
        Pr[(lane << 2) + 3] = make_float4(v[12], v[13], v[14], v[15]);
    }
    __syncthreads();   // the only barrier

    // ---- phase 2: column prefix over the 4 rows; float4 LDS reads + stores
    float4 acc = make_float4(0.f, 0.f, 0.f, 0.f);
    float4* Qo = reinterpret_cast<float4*>(Q) + (rowbase << 8) + tid;
#pragma unroll
    for (int rr = 0; rr < SEGR; ++rr) {
        const float4 h = reinterpret_cast<const float4*>(P[rr])[tid];
        acc.x += h.x; acc.y += h.y; acc.z += h.z; acc.w += h.w;
        Qo[(size_t)rr << 8] = acc;
    }
}

// ------- Kernel 2: exclusive scan of segment totals per column -------------
// Seg total of seg t = Q row (4t+3). Block = (img, 64-col group); wave w owns
// segs 64w..64w+63 in registers (coalesced 256 B loads), in-lane exclusive
// scan, cross-wave fixup via LDS. 64 blocks x 256.
__global__ __launch_bounds__(256) void segscan_kernel(const float* __restrict__ Q,
                                                      float* __restrict__ SP) {
    __shared__ float T[4][64];
    const int wave = threadIdx.x >> 6;
    const int lane = threadIdx.x & 63;
    const int img  = blockIdx.x >> 4;                    // 0..3
    const int col  = ((blockIdx.x & 15) << 6) + lane;    // 0..1023

    const float* Qi = Q + ((size_t)img << 20);
    float v[64];
#pragma unroll
    for (int s = 0; s < 64; ++s) {
        const int seg = (wave << 6) + s;
        v[s] = Qi[((size_t)((seg << 2) + 3) << 10) + col];
    }
    float run = 0.f;
#pragma unroll
    for (int s = 0; s < 64; ++s) { const float t = v[s]; v[s] = run; run += t; }
    T[wave][lane] = run;
    __syncthreads();
    float off = 0.f;
    for (int w = 0; w < wave; ++w) off += T[w][lane];    // wave-uniform trip
    float* SPo = SP + ((size_t)img << 18) + col;
#pragma unroll
    for (int s = 0; s < 64; ++s)
        SPo[(size_t)(((wave << 6) + s)) << 10] = v[s] + off;
}

// ------- Kernel 3: final — SAT window diffs ---------------------------------
// Block = (img, 4-row group), 256 threads, 32 KB LDS. Two stage+math passes:
// pass A stages Qg rows {r0+80+i, r0-81+i} (SP folded; neg rows = 0), computes
// front[i][j]; pass B stages {r0+160+i, r0-161+i}, computes allsum and out.
__global__ __launch_bounds__(256) void final_kernel(const float* __restrict__ Q,
                                                    const float* __restrict__ SP,
                                                    float* __restrict__ out) {
    __shared__ float S[8][W];        // 32768 B
    const int tid = threadIdx.x;
    const int img = blockIdx.x >> 8;
    const int r0  = (blockIdx.x & 255) << 2;

    const float4* Q4  = reinterpret_cast<const float4*>(Q)  + ((size_t)img << 18);
    const float4* SP4 = reinterpret_cast<const float4*>(SP) + ((size_t)img << 16);
    float4* S4 = reinterpret_cast<float4*>(&S[0][0]);

    // ---- pass A: stage hi1 rows (slots 0..3) and lo1 rows (slots 4..7)
#pragma unroll
    for (int i = 0; i < 4; ++i) {
        {   // hi1 = min(r0+80+i, 1023)  (always >= 0)
            const int row = min(r0 + 80 + i, H - 1);
            const float4 a = Q4[((size_t)row << 8) + tid];
            const float4 b = SP4[((size_t)(row >> 2) << 8) + tid];
            S4[(i << 8) + tid] = make_float4(a.x + b.x, a.y + b.y, a.z + b.z, a.w + b.w);
        }
        {   // lo1 = r0-81+i  (may be negative -> zeros)
            const int row = r0 - 81 + i;
            float4 vv = make_float4(0.f, 0.f, 0.f, 0.f);
            if (row >= 0) {
                const float4 a = Q4[((size_t)row << 8) + tid];
                const float4 b = SP4[((size_t)(row >> 2) << 8) + tid];
                vv = make_float4(a.x + b.x, a.y + b.y, a.z + b.z, a.w + b.w);
            }
            S4[((4 + i) << 8) + tid] = vv;
        }
    }
    __syncthreads();

    float fr[4][4];
#pragma unroll
    for (int i = 0; i < 4; ++i) {
#pragma unroll
        for (int j = 0; j < 4; ++j) {
            const int c  = tid + (j << 8);
            const int kp = min(c + 80, W - 1);
            const int km = c - 81;
            const float m = (km >= 0) ? 1.f : 0.f;
            const int k  = max(km, 0);
            fr[i][j] = (S[i][kp] - m * S[i][k]) - (S[4 + i][kp] - m * S[4 + i][k]);
        }
    }
    __syncthreads();   // before overwriting S

    // ---- pass B: stage hi3 rows (slots 0..3) and lo3 rows (slots 4..7)
#pragma unroll
    for (int i = 0; i < 4; ++i) {
        {   // hi3 = min(r0+160+i, 1023)
            const int row = min(r0 + 160 + i, H - 1);
            const float4 a = Q4[((size_t)row << 8) + tid];
            const float4 b = SP4[((size_t)(row >> 2) << 8) + tid];
            S4[(i << 8) + tid] = make_float4(a.x + b.x, a.y + b.y, a.z + b.z, a.w + b.w);
        }
        {   // lo3 = r0-161+i
            const int row = r0 - 161 + i;
            float4 vv = make_float4(0.f, 0.f, 0.f, 0.f);
            if (row >= 0) {
                const float4 a = Q4[((size_t)row << 8) + tid];
                const float4 b = SP4[((size_t)(row >> 2) << 8) + tid];
                vv = make_float4(a.x + b.x, a.y + b.y, a.z + b.z, a.w + b.w);
            }
            S4[((4 + i) << 8) + tid] = vv;
        }
    }
    __syncthreads();

    const float SCALE = (float)(77120.0 / 46657.8);   // BG_AREA / FRONT_DIV
    float* o = out + ((size_t)img << 20);
#pragma unroll
    for (int i = 0; i < 4; ++i) {
        const int r = r0 + i;
#pragma unroll
        for (int j = 0; j < 4; ++j) {
            const int c  = tid + (j << 8);
            const int kp = min(c + 160, W - 1);
            const int km = c - 161;
            const float m = (km >= 0) ? 1.f : 0.f;
            const int k  = max(km, 0);
            const float allsum = (S[i][kp] - m * S[i][k]) - (S[4 + i][kp] - m * S[4 + i][k]);
            const float front  = fr[i][j];
            o[((size_t)r << 10) + c] = SCALE * front * __builtin_amdgcn_rcpf(allsum - front);
        }
    }
}

extern "C" void kernel_launch(void* const* d_in, const int* in_sizes, int n_in,
                              void* d_out, int out_size, void* d_ws, size_t ws_size,
                              hipStream_t stream) {
    const float* x = (const float*)d_in[0];
    float* outp = (float*)d_out;
    float* Q   = (float*)d_ws;                           // 16 MB (SAT, seg-local)
    float* SPb = Q + (size_t)IMG * H * W;                // 4 MB (IMG*NSEG*W fp32)

    sat_kernel<<<dim3(IMG * NSEG), dim3(256), 0, stream>>>(x, Q);
    segscan_kernel<<<dim3(64), dim3(256), 0, stream>>>(Q, SPb);
    final_kernel<<<dim3(IMG * (H / 4)), dim3(256), 0, stream>>>(Q, SPb, outp);
}